// Round 4
// baseline (343.994 us; speedup 1.0000x reference)
//
#include <hip/hip_runtime.h>
#include <math.h>

#define B_ 8
#define T_ 4
#define N_ 2048
#define C_ 11
#define D_ 64
#define H_ 4
#define HD_ 16
#define K_ 16
#define BT_ (B_*T_)

__device__ __forceinline__ float softplus_f(float x) {
    return fmaxf(x, 0.f) + log1pf(expf(-fabsf(x)));
}

// ---- Kernel S: deterministic bitonic sort of each bt's points by (x, idx) --
// key = (ordered_uint(x) << 11) | idx  → unique → fully deterministic order.
__global__ __launch_bounds__(1024) void k_sort(const float* __restrict__ x,
    float2* __restrict__ sp2g, int* __restrict__ sidg)
{
    __shared__ unsigned long long kvs[N_];
    __shared__ float lyy[N_];
    int t = threadIdx.x, bt = blockIdx.x;
    const float* xb = x + (size_t)bt * N_ * C_;
    for (int m = t; m < N_; m += 1024) {
        float a = xb[m*C_], b = xb[m*C_+1];
        unsigned int bits = __float_as_uint(a);
        unsigned int u = (bits & 0x80000000u) ? ~bits : (bits | 0x80000000u);
        kvs[m] = ((unsigned long long)u << 11) | (unsigned)m;
        lyy[m] = b;
    }
    __syncthreads();
    for (int k = 2; k <= N_; k <<= 1) {
        for (int j = k >> 1; j > 0; j >>= 1) {
            int p = t;                                   // 1024 pairs
            int i = ((p & ~(j-1)) << 1) | (p & (j-1));
            int l = i | j;
            unsigned long long a = kvs[i], b = kvs[l];
            bool asc = (i & k) == 0;
            if ((a > b) == asc) { kvs[i] = b; kvs[l] = a; }
            __syncthreads();
        }
    }
    float2* op = sp2g + (size_t)bt * N_;
    int*    oi = sidg + (size_t)bt * N_;
    for (int m = t; m < N_; m += 1024) {
        unsigned long long key = kvs[m];
        int id = (int)(key & 0x7FFull);
        unsigned int u = (unsigned int)(key >> 11);
        unsigned int bits = (u & 0x80000000u) ? (u & 0x7FFFFFFFu) : ~u;
        op[m] = make_float2(__uint_as_float(bits), lyy[id]);
        oi[m] = id;
    }
}

// ---- Kernel A: embed MLP (BN folded) + gat_W projection + s_self, fused ----
__global__ __launch_bounds__(256) void k_embed_gatw(
    const float* __restrict__ x,
    const float* __restrict__ w1, const float* __restrict__ b1,
    const float* __restrict__ g1, const float* __restrict__ bb1,
    const float* __restrict__ m1, const float* __restrict__ v1,
    const float* __restrict__ w2, const float* __restrict__ b2,
    const float* __restrict__ g2, const float* __restrict__ bb2,
    const float* __restrict__ m2, const float* __restrict__ v2,
    const float* __restrict__ gw, const float* __restrict__ att,
    float* __restrict__ h, float* __restrict__ hw, float* __restrict__ ssf)
{
    __shared__ float sw1[32*C_], sb1[32], sw2[D_*32], sb2[D_];
    __shared__ float swg[D_*D_], sat[H_*HD_];
    int t = threadIdx.x;
    if (t < 32) {
        float s = g1[t] / sqrtf(v1[t] + 1e-5f);
        sb1[t] = (b1[t] - m1[t]) * s + bb1[t];
        for (int c = 0; c < C_; ++c) sw1[t*C_+c] = w1[t*C_+c] * s;
    } else if (t >= 64 && t < 128) {
        int j = t - 64;
        float s = g2[j] / sqrtf(v2[j] + 1e-5f);
        sb2[j] = (b2[j] - m2[j]) * s + bb2[j];
        for (int c = 0; c < 32; ++c) sw2[j*32+c] = w2[j*32+c] * s;
    }
    for (int i = t; i < D_*D_; i += 256) swg[i] = gw[i];
    if (t >= 128 && t < 192) {
        int j = t - 128;
        sat[j] = att[(j>>4)*(2*HD_) + (j & (HD_-1))];
    }
    __syncthreads();

    int node = blockIdx.x * 256 + t;
    const float* xp = x + (size_t)node * C_;
    float xin[C_];
    #pragma unroll
    for (int c = 0; c < C_; ++c) xin[c] = xp[c];

    float t1[32];
    #pragma unroll
    for (int j = 0; j < 32; ++j) {
        float a = sb1[j];
        #pragma unroll
        for (int c = 0; c < C_; ++c) a = fmaf(xin[c], sw1[j*C_+c], a);
        t1[j] = fmaxf(a, 0.f);
    }
    float hin[D_];
    float* hp = h + (size_t)node * D_;
    #pragma unroll 4
    for (int j = 0; j < D_; ++j) {
        float a = sb2[j];
        #pragma unroll
        for (int c = 0; c < 32; ++c) a = fmaf(t1[c], sw2[j*32+c], a);
        a = fmaxf(a, 0.f);
        hin[j] = a;
        hp[j] = a;
    }
    float* wp = hw + (size_t)node * D_;
    float ss[H_];
    #pragma unroll
    for (int hh = 0; hh < H_; ++hh) {
        ss[hh] = 0.f;
        #pragma unroll
        for (int jj = 0; jj < HD_; ++jj) {
            const int j = hh*HD_ + jj;
            float a = 0.f;
            const float4* wr = (const float4*)(&swg[j*D_]);
            #pragma unroll
            for (int c4 = 0; c4 < D_/4; ++c4) {
                float4 w4 = wr[c4];
                a = fmaf(hin[4*c4+0], w4.x, a);
                a = fmaf(hin[4*c4+1], w4.y, a);
                a = fmaf(hin[4*c4+2], w4.z, a);
                a = fmaf(hin[4*c4+3], w4.w, a);
            }
            wp[j] = a;
            ss[hh] = fmaf(a, sat[j], ss[hh]);
        }
    }
    float* sp2 = ssf + (size_t)node * H_;
    #pragma unroll
    for (int hh = 0; hh < H_; ++hh) sp2[hh] = ss[hh];
}

// ---- Kernel B: exact 16-NN via x-sorted two-pointer sweep, G=4/query -------
// Window expansion stops per side when next x-gap^2 >= (bd15+|q|^2)*(1+1e-4):
// conservative in float, so the exact top-16 set is preserved. Distance fma
// sequence bit-identical to the round-3 passing kernel.
__global__ __launch_bounds__(256) void k_knn(const float2* __restrict__ sp2g,
    const int* __restrict__ sidg, int* __restrict__ idx)
{
    __shared__ float2 sp[N_];
    __shared__ int sid[N_];
    __shared__ int scnt[64];
    const int bt    = blockIdx.x >> 5;          // 32 blocks per bt
    const int qbase = (blockIdx.x & 31) << 6;   // 64 queries per block
    const float2* pb = sp2g + (size_t)bt * N_;
    const int*    ib = sidg + (size_t)bt * N_;
    for (int m = threadIdx.x; m < N_; m += 256) { sp[m] = pb[m]; sid[m] = ib[m]; }
    if (threadIdx.x < 64) scnt[threadIdx.x] = 0;
    __syncthreads();

    const int q = threadIdx.x >> 2;
    const int g = threadIdx.x & 3;
    const int s = qbase + q;                    // sorted position = query
    const float xs = sp[s].x, ys = sp[s].y;
    const float sqn = __fmaf_rn(xs, xs, __fmul_rn(ys, ys));

    float bd[K_];
    #pragma unroll
    for (int i = 0; i < K_; ++i) bd[i] = 3.402823466e38f;

    int lo = s, hi = s - 1;                     // first right batch covers s
    bool ld = false, rd = false;
    while (!(ld && rd)) {
        float d[16];
        #pragma unroll
        for (int j = 0; j < 8; ++j) {
            int pl = lo - 1 - (g + 4*j);
            int ipl = pl < 0 ? 0 : pl;
            float2 p = sp[ipl];
            float sps = __fmaf_rn(p.x, p.x, __fmul_rn(p.y, p.y));
            float tt = __fmul_rn(xs, p.x);
            tt = __fmaf_rn(ys, p.y, tt);
            float dd = __fmaf_rn(-2.f, tt, sps);
            d[j] = (ld || pl < 0) ? 3.402823466e38f : dd;

            int pr = hi + 1 + (g + 4*j);
            int ipr = pr > N_-1 ? N_-1 : pr;
            float2 p2 = sp[ipr];
            float sps2 = __fmaf_rn(p2.x, p2.x, __fmul_rn(p2.y, p2.y));
            float t2 = __fmul_rn(xs, p2.x);
            t2 = __fmaf_rn(ys, p2.y, t2);
            float dd2 = __fmaf_rn(-2.f, t2, sps2);
            d[8+j] = (rd || pr > N_-1) ? 3.402823466e38f : dd2;
        }
        // bitonic sort d[0..15] ascending
        #pragma unroll
        for (int k = 2; k <= 16; k <<= 1) {
            #pragma unroll
            for (int jj = k >> 1; jj > 0; jj >>= 1) {
                #pragma unroll
                for (int ii = 0; ii < 16; ++ii) {
                    int ll = ii ^ jj;
                    if (ll > ii) {
                        float lo_ = fminf(d[ii], d[ll]);
                        float hi_ = fmaxf(d[ii], d[ll]);
                        if ((ii & k) == 0) { d[ii] = lo_; d[ll] = hi_; }
                        else               { d[ii] = hi_; d[ll] = lo_; }
                    }
                }
            }
        }
        // merge lowest-16 of (bd asc) U (d asc)
        #pragma unroll
        for (int ii = 0; ii < 16; ++ii) bd[ii] = fminf(bd[ii], d[15-ii]);
        #pragma unroll
        for (int jj = 8; jj > 0; jj >>= 1) {
            #pragma unroll
            for (int ii = 0; ii < 16; ++ii) {
                int ll = ii ^ jj;
                if (ll > ii) {
                    float lo_ = fminf(bd[ii], bd[ll]);
                    float hi_ = fmaxf(bd[ii], bd[ll]);
                    bd[ii] = lo_; bd[ll] = hi_;
                }
            }
        }
        if (!ld) lo -= 32;
        if (!rd) hi += 32;
        // group-conservative bound (min of 4 lanes' bd15 >= true d15)
        float m15 = bd[K_-1];
        m15 = fminf(m15, __shfl_xor(m15, 1, 64));
        m15 = fminf(m15, __shfl_xor(m15, 2, 64));
        float bound = (m15 + sqn) * 1.0001f + 1e-12f;
        if (!ld) {
            if (lo - 1 < 0) ld = true;
            else { float gp = xs - sp[lo-1].x; if (__fmul_rn(gp, gp) >= bound) ld = true; }
        }
        if (!rd) {
            if (hi + 1 > N_-1) rd = true;
            else { float gp = sp[hi+1].x - xs; if (__fmul_rn(gp, gp) >= bound) rd = true; }
        }
    }

    // full merge of the 4 lanes' sorted lists (2 bitonic stages)
    #pragma unroll
    for (int st = 1; st <= 2; st <<= 1) {
        float pr[K_];
        #pragma unroll
        for (int i = 0; i < K_; ++i) pr[i] = __shfl_xor(bd[K_-1-i], st, 64);
        #pragma unroll
        for (int i = 0; i < K_; ++i) bd[i] = fminf(bd[i], pr[i]);
        #pragma unroll
        for (int dd = 8; dd >= 1; dd >>= 1) {
            #pragma unroll
            for (int i = 0; i < K_; ++i) {
                if ((i & dd) == 0) {
                    float lo_ = fminf(bd[i], bd[i+dd]);
                    float hi_ = fmaxf(bd[i], bd[i+dd]);
                    bd[i] = lo_; bd[i+dd] = hi_;
                }
            }
        }
    }
    const float d15 = bd[K_-1];

    // index recovery over the final window, compact via LDS atomic
    int loF = lo < 0 ? 0 : lo;
    int hiF = hi > N_-1 ? N_-1 : hi;
    int n = sid[s];
    int* op = idx + ((size_t)bt * N_ + n) * K_;
    for (int p = loF + g; p <= hiF; p += 4) {
        float2 pp = sp[p];
        float sps = __fmaf_rn(pp.x, pp.x, __fmul_rn(pp.y, pp.y));
        float tt = __fmul_rn(xs, pp.x);
        tt = __fmaf_rn(ys, pp.y, tt);
        float dd = __fmaf_rn(-2.f, tt, sps);
        if (dd <= d15) {
            int c = atomicAdd(&scnt[q], 1);
            if (c < K_) op[c] = sid[p];
        }
    }
}

// ---- Kernel C: GAT gather + ONLINE softmax + aggregate + residual ---------
__global__ __launch_bounds__(256) void k_gat(
    const float* __restrict__ hw, const float* __restrict__ ssf,
    const int* __restrict__ idx, const float* __restrict__ att,
    float* __restrict__ h /* in-out: becomes h_sp */)
{
    int t = threadIdx.x;
    int node = blockIdx.x * 64 + (t >> 2);
    int hh = t & 3;
    int bt = node >> 11;
    const int* ip = idx + (size_t)node * K_;

    float anb[HD_];
    #pragma unroll
    for (int i = 0; i < HD_; ++i) anb[i] = att[hh*(2*HD_) + HD_ + i];
    float ssv = ssf[(size_t)node*H_ + hh];
    const float* hwb = hw + ((size_t)bt * N_) * D_;

    float m = -3.402823466e38f, den = 0.f;
    float acc[HD_];
    #pragma unroll
    for (int i = 0; i < HD_; ++i) acc[i] = 0.f;

    #pragma unroll
    for (int k = 0; k < K_; ++k) {
        int nb = ip[k];
        const float* vp = hwb + (size_t)nb*D_ + hh*HD_;
        float4 v0 = *(const float4*)(vp);
        float4 v1 = *(const float4*)(vp + 4);
        float4 v2 = *(const float4*)(vp + 8);
        float4 v3 = *(const float4*)(vp + 12);
        float a = 0.f;
        a = fmaf(v0.x, anb[0],  a); a = fmaf(v0.y, anb[1],  a);
        a = fmaf(v0.z, anb[2],  a); a = fmaf(v0.w, anb[3],  a);
        a = fmaf(v1.x, anb[4],  a); a = fmaf(v1.y, anb[5],  a);
        a = fmaf(v1.z, anb[6],  a); a = fmaf(v1.w, anb[7],  a);
        a = fmaf(v2.x, anb[8],  a); a = fmaf(v2.y, anb[9],  a);
        a = fmaf(v2.z, anb[10], a); a = fmaf(v2.w, anb[11], a);
        a = fmaf(v3.x, anb[12], a); a = fmaf(v3.y, anb[13], a);
        a = fmaf(v3.z, anb[14], a); a = fmaf(v3.w, anb[15], a);
        float s = ssv + a;
        s = (s >= 0.f) ? s : 0.2f * s;          // leaky_relu(0.2)
        float mn = fmaxf(m, s);
        float corr = __expf(m - mn);            // first iter: exp(-inf)=0
        float e = __expf(s - mn);
        den = fmaf(den, corr, e);
        acc[0]  = fmaf(acc[0],  corr, __fmul_rn(e, v0.x));
        acc[1]  = fmaf(acc[1],  corr, __fmul_rn(e, v0.y));
        acc[2]  = fmaf(acc[2],  corr, __fmul_rn(e, v0.z));
        acc[3]  = fmaf(acc[3],  corr, __fmul_rn(e, v0.w));
        acc[4]  = fmaf(acc[4],  corr, __fmul_rn(e, v1.x));
        acc[5]  = fmaf(acc[5],  corr, __fmul_rn(e, v1.y));
        acc[6]  = fmaf(acc[6],  corr, __fmul_rn(e, v1.z));
        acc[7]  = fmaf(acc[7],  corr, __fmul_rn(e, v1.w));
        acc[8]  = fmaf(acc[8],  corr, __fmul_rn(e, v2.x));
        acc[9]  = fmaf(acc[9],  corr, __fmul_rn(e, v2.y));
        acc[10] = fmaf(acc[10], corr, __fmul_rn(e, v2.z));
        acc[11] = fmaf(acc[11], corr, __fmul_rn(e, v2.w));
        acc[12] = fmaf(acc[12], corr, __fmul_rn(e, v3.x));
        acc[13] = fmaf(acc[13], corr, __fmul_rn(e, v3.y));
        acc[14] = fmaf(acc[14], corr, __fmul_rn(e, v3.z));
        acc[15] = fmaf(acc[15], corr, __fmul_rn(e, v3.w));
        m = mn;
    }
    float inv = 1.f / den;
    float* hp = h + (size_t)node*D_ + hh*HD_;
    #pragma unroll
    for (int i = 0; i < HD_; ++i) hp[i] = fmaxf(fmaf(acc[i], inv, hp[i]), 0.f);
}

// ---- Kernel D1: Q and KV projections ----
__global__ __launch_bounds__(256) void k_qkv(
    const float* __restrict__ hsp,
    const float* __restrict__ qw, const float* __restrict__ qb,
    const float* __restrict__ kw, const float* __restrict__ kb,
    float* __restrict__ q, float* __restrict__ kv)
{
    __shared__ float s_qw[D_*D_], s_kw[D_*D_], s_qb[D_], s_kb[D_];
    int t = threadIdx.x;
    for (int i = t; i < D_*D_; i += 256) { s_qw[i] = qw[i]; s_kw[i] = kw[i]; }
    if (t < D_) { s_qb[t] = qb[t]; s_kb[t] = kb[t]; }
    __syncthreads();

    int r = blockIdx.x * 256 + t;
    const float* in; float* outp; const float* W; const float* bb;
    if (r < BT_*N_) {
        int bt = r >> 11; int n = r & (N_-1);
        int b = bt >> 2, tt = bt & 3;
        in = hsp + (size_t)r * D_;
        outp = kv + (((size_t)(b*N_ + n))*T_ + tt) * D_;
        W = s_kw; bb = s_kb;
    } else {
        int rr = r - BT_*N_;
        int b = rr >> 11, n = rr & (N_-1);
        in = hsp + ((size_t)(b*T_ + (T_-1))*N_ + n) * D_;
        outp = q + (size_t)rr * D_;
        W = s_qw; bb = s_qb;
    }
    float xin[D_];
    #pragma unroll
    for (int j = 0; j < D_; j += 4) {
        float4 v = *(const float4*)(in + j);
        xin[j] = v.x; xin[j+1] = v.y; xin[j+2] = v.z; xin[j+3] = v.w;
    }
    #pragma unroll 4
    for (int j = 0; j < D_; ++j) {
        float a = bb[j];
        const float4* wr = (const float4*)(&W[j*D_]);
        #pragma unroll
        for (int c4 = 0; c4 < D_/4; ++c4) {
            float4 w4 = wr[c4];
            a = fmaf(xin[4*c4+0], w4.x, a);
            a = fmaf(xin[4*c4+1], w4.y, a);
            a = fmaf(xin[4*c4+2], w4.z, a);
            a = fmaf(xin[4*c4+3], w4.w, a);
        }
        outp[j] = a;
    }
}

// ---- Kernel D2: temporal attention + output heads ----
__global__ __launch_bounds__(64) void k_head(
    const float* __restrict__ q, const float* __restrict__ kv,
    const float* __restrict__ lw1, const float* __restrict__ lb1,
    const float* __restrict__ lw2, const float* __restrict__ lb2,
    const float* __restrict__ rw1, const float* __restrict__ rb1,
    const float* __restrict__ rw2, const float* __restrict__ rb2,
    float* __restrict__ out)
{
    __shared__ float sl1[32*D_], sr1[32*D_], sl2[4*32], sr2[4*32];
    __shared__ float slb1[32], srb1[32], slb2[4], srb2[4];
    int t = threadIdx.x;
    for (int i = t; i < 32*D_; i += 64) { sl1[i] = lw1[i]; sr1[i] = rw1[i]; }
    for (int i = t; i < 128; i += 64)   { sl2[i] = lw2[i]; sr2[i] = rw2[i]; }
    if (t < 32) { slb1[t] = lb1[t]; srb1[t] = rb1[t]; }
    if (t < 4)  { slb2[t] = lb2[t]; srb2[t] = rb2[t]; }
    __syncthreads();

    int rn = blockIdx.x * 64 + t;
    const float* qp = q + (size_t)rn * D_;
    const float* kp = kv + (size_t)rn * T_ * D_;

    float qv[D_];
    #pragma unroll
    for (int j = 0; j < D_; j += 4) {
        float4 v = *(const float4*)(qp + j);
        qv[j] = v.x; qv[j+1] = v.y; qv[j+2] = v.z; qv[j+3] = v.w;
    }
    float scv[T_];
    #pragma unroll
    for (int tt = 0; tt < T_; ++tt) {
        float a = 0.f;
        const float4* kr = (const float4*)(kp + tt*D_);
        #pragma unroll
        for (int c4 = 0; c4 < D_/4; ++c4) {
            float4 v = kr[c4];
            a = fmaf(qv[4*c4+0], v.x, a);
            a = fmaf(qv[4*c4+1], v.y, a);
            a = fmaf(qv[4*c4+2], v.z, a);
            a = fmaf(qv[4*c4+3], v.w, a);
        }
        scv[tt] = a * 0.125f;
    }
    float mx = fmaxf(fmaxf(scv[0], scv[1]), fmaxf(scv[2], scv[3]));
    float wsum = 0.f;
    #pragma unroll
    for (int tt = 0; tt < T_; ++tt) { scv[tt] = expf(scv[tt] - mx); wsum += scv[tt]; }
    float winv = 1.f / wsum;

    float hf[D_];
    #pragma unroll
    for (int j = 0; j < D_; ++j) hf[j] = 0.f;
    #pragma unroll
    for (int tt = 0; tt < T_; ++tt) {
        float w = scv[tt] * winv;
        const float4* kr = (const float4*)(kp + tt*D_);
        #pragma unroll
        for (int c4 = 0; c4 < D_/4; ++c4) {
            float4 v = kr[c4];
            hf[4*c4+0] = fmaf(v.x, w, hf[4*c4+0]);
            hf[4*c4+1] = fmaf(v.y, w, hf[4*c4+1]);
            hf[4*c4+2] = fmaf(v.z, w, hf[4*c4+2]);
            hf[4*c4+3] = fmaf(v.w, w, hf[4*c4+3]);
        }
    }
    float ol0 = slb2[0], ol1 = slb2[1], ol2 = slb2[2], ol3 = slb2[3];
    #pragma unroll 2
    for (int j = 0; j < 32; ++j) {
        float a = slb1[j];
        const float4* wr = (const float4*)(&sl1[j*D_]);
        #pragma unroll
        for (int c4 = 0; c4 < D_/4; ++c4) {
            float4 v = wr[c4];
            a = fmaf(hf[4*c4+0], v.x, a);
            a = fmaf(hf[4*c4+1], v.y, a);
            a = fmaf(hf[4*c4+2], v.z, a);
            a = fmaf(hf[4*c4+3], v.w, a);
        }
        a = fmaxf(a, 0.f);
        ol0 = fmaf(a, sl2[0*32+j], ol0);
        ol1 = fmaf(a, sl2[1*32+j], ol1);
        ol2 = fmaf(a, sl2[2*32+j], ol2);
        ol3 = fmaf(a, sl2[3*32+j], ol3);
    }
    float or0 = srb2[0], or1 = srb2[1], or2 = srb2[2], or3 = srb2[3];
    #pragma unroll 2
    for (int j = 0; j < 32; ++j) {
        float a = srb1[j];
        const float4* wr = (const float4*)(&sr1[j*D_]);
        #pragma unroll
        for (int c4 = 0; c4 < D_/4; ++c4) {
            float4 v = wr[c4];
            a = fmaf(hf[4*c4+0], v.x, a);
            a = fmaf(hf[4*c4+1], v.y, a);
            a = fmaf(hf[4*c4+2], v.z, a);
            a = fmaf(hf[4*c4+3], v.w, a);
        }
        a = fmaxf(a, 0.f);
        or0 = fmaf(a, sr2[0*32+j], or0);
        or1 = fmaf(a, sr2[1*32+j], or1);
        or2 = fmaf(a, sr2[2*32+j], or2);
        or3 = fmaf(a, sr2[3*32+j], or3);
    }
    const int NB = B_ * N_;
    out[0*2*NB + rn*2 + 0] = ol0;
    out[0*2*NB + rn*2 + 1] = ol1;
    out[1*2*NB + rn*2 + 0] = softplus_f(ol2) + 1e-6f;
    out[1*2*NB + rn*2 + 1] = softplus_f(ol3) + 1e-6f;
    out[2*2*NB + rn*2 + 0] = or0;
    out[2*2*NB + rn*2 + 1] = or1;
    out[3*2*NB + rn*2 + 0] = softplus_f(or2) + 1e-6f;
    out[3*2*NB + rn*2 + 1] = softplus_f(or3) + 1e-6f;
}

// ---- launcher ----
extern "C" void kernel_launch(void* const* d_in, const int* in_sizes, int n_in,
                              void* d_out, int out_size, void* d_ws, size_t ws_size,
                              hipStream_t stream)
{
    const float* x   = (const float*)d_in[0];
    const float* ew1 = (const float*)d_in[1];
    const float* eb1 = (const float*)d_in[2];
    const float* g1  = (const float*)d_in[3];
    const float* bb1 = (const float*)d_in[4];
    const float* m1  = (const float*)d_in[5];
    const float* v1  = (const float*)d_in[6];
    const float* ew2 = (const float*)d_in[7];
    const float* eb2 = (const float*)d_in[8];
    const float* g2  = (const float*)d_in[9];
    const float* bb2 = (const float*)d_in[10];
    const float* m2  = (const float*)d_in[11];
    const float* v2  = (const float*)d_in[12];
    const float* gw  = (const float*)d_in[13];
    const float* att = (const float*)d_in[14];
    const float* qw  = (const float*)d_in[15];
    const float* qb  = (const float*)d_in[16];
    const float* kw  = (const float*)d_in[17];
    const float* kb  = (const float*)d_in[18];
    const float* lw1 = (const float*)d_in[19];
    const float* lb1 = (const float*)d_in[20];
    const float* lw2 = (const float*)d_in[21];
    const float* lb2 = (const float*)d_in[22];
    const float* rw1 = (const float*)d_in[23];
    const float* rb1 = (const float*)d_in[24];
    const float* rw2 = (const float*)d_in[25];
    const float* rb2 = (const float*)d_in[26];
    float* out = (float*)d_out;

    float* h   = (float*)d_ws;                               // BT*N*64
    float* hw  = h   + (size_t)BT_*N_*D_;                    // BT*N*64
    float* ssf = hw  + (size_t)BT_*N_*D_;                    // BT*N*4
    int*   idx = (int*)(ssf + (size_t)BT_*N_*H_);            // BT*N*16
    float* q   = (float*)(idx + (size_t)BT_*N_*K_);          // B*N*64
    float* kv  = hw;                   // hw dead after k_gat
    float2* sp2g = (float2*)q;         // sorted arrays live in q region
    int*    sidg = (int*)(q + 2*(size_t)BT_*N_);  // (dead before k_qkv writes q)

    k_sort<<<BT_, 1024, 0, stream>>>(x, sp2g, sidg);
    k_embed_gatw<<<BT_*N_/256, 256, 0, stream>>>(x, ew1, eb1, g1, bb1, m1, v1,
                                                 ew2, eb2, g2, bb2, m2, v2,
                                                 gw, att, h, hw, ssf);
    k_knn<<<BT_*(N_/64), 256, 0, stream>>>(sp2g, sidg, idx);
    k_gat<<<(BT_*N_*H_)/256, 256, 0, stream>>>(hw, ssf, idx, att, h);
    k_qkv<<<(BT_*N_ + B_*N_)/256, 256, 0, stream>>>(h, qw, qb, kw, kb, q, kv);
    k_head<<<(B_*N_)/64, 64, 0, stream>>>(q, kv, lw1, lb1, lw2, lb2,
                                          rw1, rb1, rw2, rb2, out);
}